// Round 1
// baseline (662.121 us; speedup 1.0000x reference)
//
#include <hip/hip_runtime.h>

// Sparse residual block: conv3x3x3(x,W1)+BN+ReLU -> conv3x3x3(h,W2)+BN, skip = BN(x@Wd),
// out = relu(h2 + skip). Output-centric formulation via inverted kernel map (no atomics).

constexpr int K    = 27;
constexpr int CIN  = 64;
constexpr int COUT = 96;
constexpr int CPT  = 24;              // couts per thread; one wave (64 rows) per cout-group
constexpr int ROWS_PER_BLOCK = 64;    // 4 waves/block: wave w handles couts [24w, 24w+24)

// --- invert (k, pos) -> (out row, k) neighbor table -------------------------
__global__ void build_nb_kernel(const int* __restrict__ in_idx,
                                const int* __restrict__ out_idx,
                                int* __restrict__ nb, int N) {
  int t = blockIdx.x * blockDim.x + threadIdx.x;
  if (t >= K * N) return;
  int k = t / N;
  int o = out_idx[t];
  if (o < N) nb[(long)o * K + k] = in_idx[t];   // unique (o,k) per construction
}

// --- accumulate one gathered input row into 24 cout accumulators ------------
// wk points at W[k] column-offset co0 (wave-uniform -> s_load weight traffic)
template <int CI>
__device__ __forceinline__ void accum_row(const float* __restrict__ xr,
                                          const float* __restrict__ wk,
                                          float acc[CPT]) {
#pragma unroll
  for (int c4 = 0; c4 < CI / 4; ++c4) {
    float4 xv = *reinterpret_cast<const float4*>(xr + c4 * 4);
#pragma unroll
    for (int cc = 0; cc < 4; ++cc) {
      float xs = (&xv.x)[cc];
      const float* wrow = wk + (c4 * 4 + cc) * COUT;
#pragma unroll
      for (int q = 0; q < CPT / 4; ++q) {
        float4 wv = *reinterpret_cast<const float4*>(wrow + q * 4);
        acc[q * 4 + 0] = fmaf(xs, wv.x, acc[q * 4 + 0]);
        acc[q * 4 + 1] = fmaf(xs, wv.y, acc[q * 4 + 1]);
        acc[q * 4 + 2] = fmaf(xs, wv.z, acc[q * 4 + 2]);
        acc[q * 4 + 3] = fmaf(xs, wv.w, acc[q * 4 + 3]);
      }
    }
  }
}

// --- conv1 + BN1 + ReLU -> h ------------------------------------------------
__global__ __launch_bounds__(256) void conv1_kernel(
    const float* __restrict__ x, const float* __restrict__ W1,
    const float* __restrict__ g, const float* __restrict__ b,
    const float* __restrict__ m, const float* __restrict__ v,
    const int* __restrict__ nb, float* __restrict__ h, int N) {
  const int lane = threadIdx.x & 63;
  const int co0  = __builtin_amdgcn_readfirstlane((int)(threadIdx.x >> 6) * CPT);
  const int row  = blockIdx.x * ROWS_PER_BLOCK + lane;
  if (row >= N) return;

  float acc[CPT];
#pragma unroll
  for (int i = 0; i < CPT; ++i) acc[i] = 0.f;

  const int* nbr = nb + (long)row * K;
  for (int k = 0; k < K; ++k) {
    int j = nbr[k];
    if (j >= 0) {  // whole-wave invalid -> s_cbranch_execz skips the FMA block
      accum_row<CIN>(x + (long)j * CIN, W1 + (long)k * CIN * COUT + co0, acc);
    }
  }

  float* hr = h + (long)row * COUT + co0;
#pragma unroll
  for (int q = 0; q < CPT / 4; ++q) {
    float4 o;
#pragma unroll
    for (int cc = 0; cc < 4; ++cc) {
      int c = co0 + q * 4 + cc;
      float s   = g[c] * rsqrtf(v[c] + 1e-5f);
      float val = (acc[q * 4 + cc] - m[c]) * s + b[c];
      (&o.x)[cc] = fmaxf(val, 0.f);
    }
    *reinterpret_cast<float4*>(hr + q * 4) = o;
  }
}

// --- conv2 + BN2 + skip(BN(x@Wd)) + ReLU -> out ------------------------------
__global__ __launch_bounds__(256) void conv2_kernel(
    const float* __restrict__ hfeat, const float* __restrict__ W2,
    const float* __restrict__ g2, const float* __restrict__ b2,
    const float* __restrict__ m2, const float* __restrict__ v2,
    const float* __restrict__ x, const float* __restrict__ Wd,
    const float* __restrict__ gd, const float* __restrict__ bd,
    const float* __restrict__ md, const float* __restrict__ vd,
    const int* __restrict__ nb, float* __restrict__ out, int N) {
  const int lane = threadIdx.x & 63;
  const int co0  = __builtin_amdgcn_readfirstlane((int)(threadIdx.x >> 6) * CPT);
  const int row  = blockIdx.x * ROWS_PER_BLOCK + lane;
  if (row >= N) return;

  float acc[CPT];
#pragma unroll
  for (int i = 0; i < CPT; ++i) acc[i] = 0.f;

  const int* nbr = nb + (long)row * K;
  for (int k = 0; k < K; ++k) {
    int j = nbr[k];
    if (j >= 0) {
      accum_row<COUT>(hfeat + (long)j * COUT, W2 + (long)k * COUT * COUT + co0, acc);
    }
  }

  // skip path: x @ Wd (always-valid, own row)
  float sk[CPT];
#pragma unroll
  for (int i = 0; i < CPT; ++i) sk[i] = 0.f;
  accum_row<CIN>(x + (long)row * CIN, Wd + co0, sk);

  float* orow = out + (long)row * COUT + co0;
#pragma unroll
  for (int q = 0; q < CPT / 4; ++q) {
    float4 o;
#pragma unroll
    for (int cc = 0; cc < 4; ++cc) {
      int c  = co0 + q * 4 + cc;
      float s2 = g2[c] * rsqrtf(v2[c] + 1e-5f);
      float hv = (acc[q * 4 + cc] - m2[c]) * s2 + b2[c];
      float sd = gd[c] * rsqrtf(vd[c] + 1e-5f);
      float sv = (sk[q * 4 + cc] - md[c]) * sd + bd[c];
      (&o.x)[cc] = fmaxf(hv + sv, 0.f);
    }
    *reinterpret_cast<float4*>(orow + q * 4) = o;
  }
}

extern "C" void kernel_launch(void* const* d_in, const int* in_sizes, int n_in,
                              void* d_out, int out_size, void* d_ws, size_t ws_size,
                              hipStream_t stream) {
  const float* x   = (const float*)d_in[0];
  const float* W1  = (const float*)d_in[1];
  const float* g1  = (const float*)d_in[2];
  const float* b1  = (const float*)d_in[3];
  const float* m1  = (const float*)d_in[4];
  const float* v1  = (const float*)d_in[5];
  const float* W2  = (const float*)d_in[6];
  const float* g2  = (const float*)d_in[7];
  const float* b2  = (const float*)d_in[8];
  const float* m2  = (const float*)d_in[9];
  const float* v2  = (const float*)d_in[10];
  const float* Wd  = (const float*)d_in[11];
  const float* gd  = (const float*)d_in[12];
  const float* bd  = (const float*)d_in[13];
  const float* md  = (const float*)d_in[14];
  const float* vd  = (const float*)d_in[15];
  const int* in_idx  = (const int*)d_in[16];
  const int* out_idx = (const int*)d_in[17];

  const int N = in_sizes[0] / CIN;

  // workspace: nb table (N*K int) | h (N*COUT float)
  char* ws = (char*)d_ws;
  int*   nb = (int*)ws;
  size_t nbBytes = (size_t)N * K * sizeof(int);
  float* h  = (float*)(ws + ((nbBytes + 255) & ~(size_t)255));

  hipMemsetAsync(nb, 0xFF, nbBytes, stream);  // -1 fill
  int total = K * N;
  build_nb_kernel<<<(total + 255) / 256, 256, 0, stream>>>(in_idx, out_idx, nb, N);

  int blocks = (N + ROWS_PER_BLOCK - 1) / ROWS_PER_BLOCK;
  conv1_kernel<<<blocks, 256, 0, stream>>>(x, W1, g1, b1, m1, v1, nb, h, N);
  conv2_kernel<<<blocks, 256, 0, stream>>>(h, W2, g2, b2, m2, v2,
                                           x, Wd, gd, bd, md, vd,
                                           nb, (float*)d_out, N);
}

// Round 2
// 422.277 us; speedup vs baseline: 1.5680x; 1.5680x over previous
//
#include <hip/hip_runtime.h>

// Sparse residual block via bf16 MFMA, output-centric (no atomics).
// conv1: h = relu(bn1(conv(x,W1)));  conv2: out = relu(bn2(conv(h,W2)) + bnd(x@Wd))
// Per wave: 32 output rows x 48 couts. A = gathered rows (invalid -> zero row),
// B = pre-transposed bf16 weights [k][cout][cin].

typedef __attribute__((ext_vector_type(8))) short bf16x8;
typedef __attribute__((ext_vector_type(4))) float f32x4;
typedef unsigned short u16;

constexpr int K    = 27;
constexpr int CIN  = 64;
constexpr int COUT = 96;
constexpr int NF   = 3;    // 16-col fragments per wave (48 couts); 2 wave-halves cover 96

__device__ __forceinline__ u16 f2bf(float f) {
  unsigned int u = __float_as_uint(f);
  unsigned int r = (u + 0x7FFFu + ((u >> 16) & 1u)) >> 16;  // RN-even
  return (u16)r;
}

// MFMA fragment load: elems 0-3 at p[g4..g4+3], elems 4-7 at p[g4+16..g4+19]
// -> k_local = 4*(lane>>4) + (j&3) + 16*(j>>2), matching gfx950 16x16x32 layout.
__device__ __forceinline__ bf16x8 load_frag(const u16* p, int g4) {
  union { bf16x8 f; uint4 u; } r;
  uint2 lo = *reinterpret_cast<const uint2*>(p + g4);
  uint2 hi = *reinterpret_cast<const uint2*>(p + g4 + 16);
  r.u.x = lo.x; r.u.y = lo.y; r.u.z = hi.x; r.u.w = hi.y;
  return r.f;
}

// ---------------- prep kernels ----------------
__global__ void build_nbT(const int* __restrict__ in_idx, const int* __restrict__ out_idx,
                          int* __restrict__ nbT, int N, int N_pad) {
  int t = blockIdx.x * blockDim.x + threadIdx.x;
  if (t >= K * N) return;
  int k = t / N;
  int o = out_idx[t];
  if (o < N) nbT[k * N_pad + o] = in_idx[t];   // unique (o,k); padding rows stay -1
}

__global__ void cvt_x(const float* __restrict__ x, u16* __restrict__ xbf, int N) {
  int i = blockIdx.x * blockDim.x + threadIdx.x;
  if (i < (N + 1) * CIN) xbf[i] = (i < N * CIN) ? f2bf(x[i]) : (u16)0;
}

__global__ void cvt_w1t(const float* __restrict__ W, u16* __restrict__ Wt) {
  int i = blockIdx.x * blockDim.x + threadIdx.x;
  if (i >= K * COUT * CIN) return;
  int k = i / (COUT * CIN), rem = i % (COUT * CIN);
  int co = rem / CIN, ci = rem % CIN;
  Wt[i] = f2bf(W[k * CIN * COUT + ci * COUT + co]);
}

__global__ void cvt_w2t(const float* __restrict__ W, u16* __restrict__ Wt) {
  int i = blockIdx.x * blockDim.x + threadIdx.x;
  if (i >= K * COUT * COUT) return;
  int k = i / (COUT * COUT), rem = i % (COUT * COUT);
  int co = rem / COUT, ci = rem % COUT;
  Wt[i] = f2bf(W[k * COUT * COUT + ci * COUT + co]);
}

__global__ void cvt_wdt(const float* __restrict__ W, u16* __restrict__ Wt) {
  int i = blockIdx.x * blockDim.x + threadIdx.x;
  if (i >= COUT * CIN) return;
  int co = i / CIN, ci = i % CIN;
  Wt[i] = f2bf(W[ci * COUT + co]);
}

__global__ void bn_prep(const float* g1, const float* b1, const float* m1, const float* v1,
                        const float* g2, const float* b2, const float* m2, const float* v2,
                        const float* gd, const float* bd, const float* md, const float* vd,
                        float* __restrict__ bnc, u16* __restrict__ hbf, int N) {
  int c = threadIdx.x;
  if (c < COUT) {
    float A1 = g1[c] * rsqrtf(v1[c] + 1e-5f);
    float A2 = g2[c] * rsqrtf(v2[c] + 1e-5f);
    float Ad = gd[c] * rsqrtf(vd[c] + 1e-5f);
    bnc[c]        = A1;
    bnc[96 + c]   = b1[c] - m1[c] * A1;
    bnc[192 + c]  = A2;
    bnc[288 + c]  = b2[c] - m2[c] * A2 + bd[c] - md[c] * Ad;
    bnc[384 + c]  = Ad / A2;
    hbf[N * COUT + c] = 0;  // zero row for invalid gathers
  }
}

// ---------------- conv1: x (CIN) -> h (COUT) bf16, BN+ReLU ----------------
__global__ __launch_bounds__(256) void conv1_mfma(
    const u16* __restrict__ xbf, const u16* __restrict__ W1t,
    const int* __restrict__ nbT, const float* __restrict__ bnc,
    u16* __restrict__ hbf, int N, int N_pad) {
  const int lane  = threadIdx.x & 63;
  const int wv    = threadIdx.x >> 6;
  const int m     = lane & 15;
  const int g4    = ((lane >> 4) & 3) * 4;
  const int tile0 = blockIdx.x * 64 + (wv >> 1) * 32;   // 32 rows per wave
  const int n0    = (wv & 1) * NF;                      // cout half

  f32x4 acc[2][NF];
  const f32x4 zero = {0.f, 0.f, 0.f, 0.f};
#pragma unroll
  for (int s = 0; s < 2; ++s)
#pragma unroll
    for (int n = 0; n < NF; ++n) acc[s][n] = zero;

  for (int k = 0; k < K; ++k) {
    const int* nbk = nbT + k * N_pad + tile0 + m;
    int j0 = nbk[0];
    int j1 = nbk[16];
    const u16* a0p = xbf + (j0 < 0 ? N : j0) * CIN;
    const u16* a1p = xbf + (j1 < 0 ? N : j1) * CIN;
    const u16* wb  = W1t + k * (COUT * CIN) + (n0 * 16 + m) * CIN;
#pragma unroll
    for (int c = 0; c < CIN; c += 32) {
      bf16x8 A0 = load_frag(a0p + c, g4);
      bf16x8 A1 = load_frag(a1p + c, g4);
#pragma unroll
      for (int n = 0; n < NF; ++n) {
        bf16x8 B = load_frag(wb + n * 16 * CIN + c, g4);
        acc[0][n] = __builtin_amdgcn_mfma_f32_16x16x32_bf16(A0, B, acc[0][n], 0, 0, 0);
        acc[1][n] = __builtin_amdgcn_mfma_f32_16x16x32_bf16(A1, B, acc[1][n], 0, 0, 0);
      }
    }
  }

#pragma unroll
  for (int n = 0; n < NF; ++n) {
    const int col = (n0 + n) * 16 + m;
    const float s = bnc[col], b = bnc[96 + col];
#pragma unroll
    for (int st = 0; st < 2; ++st) {
      const int rbase = tile0 + st * 16 + g4;
#pragma unroll
      for (int r = 0; r < 4; ++r) {
        const int row = rbase + r;
        if (row < N) {
          float v = fmaxf(fmaf(acc[st][n][r], s, b), 0.f);
          hbf[row * COUT + col] = f2bf(v);
        }
      }
    }
  }
}

// -------- conv2: h (COUT) -> out fp32, + folded skip BN(x@Wd), BN+ReLU --------
__global__ __launch_bounds__(256) void conv2_mfma(
    const u16* __restrict__ hbf, const u16* __restrict__ W2t,
    const u16* __restrict__ xbf, const u16* __restrict__ Wdt,
    const int* __restrict__ nbT, const float* __restrict__ bnc,
    float* __restrict__ out, int N, int N_pad) {
  const int lane  = threadIdx.x & 63;
  const int wv    = threadIdx.x >> 6;
  const int m     = lane & 15;
  const int g4    = ((lane >> 4) & 3) * 4;
  const int tile0 = blockIdx.x * 64 + (wv >> 1) * 32;
  const int n0    = (wv & 1) * NF;

  f32x4 acc[2][NF];
  const f32x4 zero = {0.f, 0.f, 0.f, 0.f};
#pragma unroll
  for (int s = 0; s < 2; ++s)
#pragma unroll
    for (int n = 0; n < NF; ++n) acc[s][n] = zero;

  // skip path first: acc = x @ Wd (own rows), then scaled by Ad/A2
  {
    int r0 = tile0 + m, r1 = tile0 + 16 + m;
    const u16* a0p = xbf + (r0 < N ? r0 : N) * CIN;
    const u16* a1p = xbf + (r1 < N ? r1 : N) * CIN;
    const u16* wb  = Wdt + (n0 * 16 + m) * CIN;
#pragma unroll
    for (int c = 0; c < CIN; c += 32) {
      bf16x8 A0 = load_frag(a0p + c, g4);
      bf16x8 A1 = load_frag(a1p + c, g4);
#pragma unroll
      for (int n = 0; n < NF; ++n) {
        bf16x8 B = load_frag(wb + n * 16 * CIN + c, g4);
        acc[0][n] = __builtin_amdgcn_mfma_f32_16x16x32_bf16(A0, B, acc[0][n], 0, 0, 0);
        acc[1][n] = __builtin_amdgcn_mfma_f32_16x16x32_bf16(A1, B, acc[1][n], 0, 0, 0);
      }
    }
  }
#pragma unroll
  for (int n = 0; n < NF; ++n) {
    float rr = bnc[384 + (n0 + n) * 16 + m];  // Ad/A2
    acc[0][n] *= rr;
    acc[1][n] *= rr;
  }

  for (int k = 0; k < K; ++k) {
    const int* nbk = nbT + k * N_pad + tile0 + m;
    int j0 = nbk[0];
    int j1 = nbk[16];
    const u16* a0p = hbf + (j0 < 0 ? N : j0) * COUT;
    const u16* a1p = hbf + (j1 < 0 ? N : j1) * COUT;
    const u16* wb  = W2t + k * (COUT * COUT) + (n0 * 16 + m) * COUT;
#pragma unroll
    for (int c = 0; c < COUT; c += 32) {
      bf16x8 A0 = load_frag(a0p + c, g4);
      bf16x8 A1 = load_frag(a1p + c, g4);
#pragma unroll
      for (int n = 0; n < NF; ++n) {
        bf16x8 B = load_frag(wb + n * 16 * COUT + c, g4);
        acc[0][n] = __builtin_amdgcn_mfma_f32_16x16x32_bf16(A0, B, acc[0][n], 0, 0, 0);
        acc[1][n] = __builtin_amdgcn_mfma_f32_16x16x32_bf16(A1, B, acc[1][n], 0, 0, 0);
      }
    }
  }

#pragma unroll
  for (int n = 0; n < NF; ++n) {
    const int col = (n0 + n) * 16 + m;
    const float s = bnc[192 + col], b = bnc[288 + col];
#pragma unroll
    for (int st = 0; st < 2; ++st) {
      const int rbase = tile0 + st * 16 + g4;
#pragma unroll
      for (int r = 0; r < 4; ++r) {
        const int row = rbase + r;
        if (row < N) out[row * COUT + col] = fmaxf(fmaf(acc[st][n][r], s, b), 0.f);
      }
    }
  }
}

// ---------------- launch ----------------
extern "C" void kernel_launch(void* const* d_in, const int* in_sizes, int n_in,
                              void* d_out, int out_size, void* d_ws, size_t ws_size,
                              hipStream_t stream) {
  const float* x   = (const float*)d_in[0];
  const float* W1  = (const float*)d_in[1];
  const float* g1  = (const float*)d_in[2];
  const float* b1  = (const float*)d_in[3];
  const float* m1  = (const float*)d_in[4];
  const float* v1  = (const float*)d_in[5];
  const float* W2  = (const float*)d_in[6];
  const float* g2  = (const float*)d_in[7];
  const float* b2  = (const float*)d_in[8];
  const float* m2  = (const float*)d_in[9];
  const float* v2  = (const float*)d_in[10];
  const float* Wd  = (const float*)d_in[11];
  const float* gd  = (const float*)d_in[12];
  const float* bd  = (const float*)d_in[13];
  const float* md  = (const float*)d_in[14];
  const float* vd  = (const float*)d_in[15];
  const int* in_idx  = (const int*)d_in[16];
  const int* out_idx = (const int*)d_in[17];

  const int N  = in_sizes[0] / CIN;
  const int GB = (N + 63) / 64;        // blocks for conv kernels (64 rows each)
  const int N_pad = GB * 64;

  char* ws = (char*)d_ws;
  size_t off = 0;
  auto alloc = [&](size_t bytes) { size_t o = off; off = (off + bytes + 255) & ~(size_t)255; return o; };
  int*   nbT = (int*)(ws + alloc((size_t)K * N_pad * sizeof(int)));
  u16*   xbf = (u16*)(ws + alloc((size_t)(N + 1) * CIN * sizeof(u16)));
  u16*   hbf = (u16*)(ws + alloc((size_t)(N + 1) * COUT * sizeof(u16)));
  u16*   W1t = (u16*)(ws + alloc((size_t)K * COUT * CIN * sizeof(u16)));
  u16*   W2t = (u16*)(ws + alloc((size_t)K * COUT * COUT * sizeof(u16)));
  u16*   Wdt = (u16*)(ws + alloc((size_t)COUT * CIN * sizeof(u16)));
  float* bnc = (float*)(ws + alloc(5 * 96 * sizeof(float)));

  hipMemsetAsync(nbT, 0xFF, (size_t)K * N_pad * sizeof(int), stream);
  build_nbT<<<(K * N + 255) / 256, 256, 0, stream>>>(in_idx, out_idx, nbT, N, N_pad);
  cvt_x<<<((N + 1) * CIN + 255) / 256, 256, 0, stream>>>(x, xbf, N);
  cvt_w1t<<<(K * COUT * CIN + 255) / 256, 256, 0, stream>>>(W1, W1t);
  cvt_w2t<<<(K * COUT * COUT + 255) / 256, 256, 0, stream>>>(W2, W2t);
  cvt_wdt<<<(COUT * CIN + 255) / 256, 256, 0, stream>>>(Wd, Wdt);
  bn_prep<<<1, 128, 0, stream>>>(g1, b1, m1, v1, g2, b2, m2, v2, gd, bd, md, vd, bnc, hbf, N);

  conv1_mfma<<<GB, 256, 0, stream>>>(xbf, W1t, nbT, bnc, hbf, N, N_pad);
  conv2_mfma<<<GB, 256, 0, stream>>>(hbf, W2t, xbf, Wdt, nbT, bnc, (float*)d_out, N, N_pad);
}

// Round 3
// 329.197 us; speedup vs baseline: 2.0113x; 1.2827x over previous
//
#include <hip/hip_runtime.h>

// Sparse residual block via bf16 MFMA, output-centric, fully register-pipelined.
// Layout trick: channels stored permuted within 32-chunks so each MFMA fragment
// (A and B) is ONE contiguous 16B load: pos(c)=((c>>2)&3)*8+(c&3)+((c>>4)&1)*4.

typedef __attribute__((ext_vector_type(8))) short bf16x8;
typedef __attribute__((ext_vector_type(4))) float f32x4;
typedef unsigned short u16;

constexpr int K27  = 27;
constexpr int CIN  = 64;
constexpr int COUT = 96;

#define MFMA __builtin_amdgcn_mfma_f32_16x16x32_bf16

__device__ __forceinline__ u16 f2bf(float f) {
  unsigned u = __float_as_uint(f);
  return (u16)((u + 0x7FFFu + ((u >> 16) & 1u)) >> 16);
}

__device__ __forceinline__ int posf(int c) {  // c in 0..31
  return ((c >> 2) & 3) * 8 + (c & 3) + ((c >> 4) & 1) * 4;
}

__device__ __forceinline__ bf16x8 ld16(const u16* p) {
  union { bf16x8 f; uint4 u; } r;
  r.u = *reinterpret_cast<const uint4*>(p);
  return r.f;
}

// ---------------- prep ----------------
__global__ void build_nbT(const int* __restrict__ in_idx, const int* __restrict__ out_idx,
                          int* __restrict__ nbT, int N, int N_pad) {
  int t = blockIdx.x * blockDim.x + threadIdx.x;
  if (t >= K27 * N) return;
  int k = t / N;
  int o = out_idx[t];
  if (o < N) nbT[(size_t)k * N_pad + o] = in_idx[t];
}

__global__ void cvt_x(const float* __restrict__ x, u16* __restrict__ xbf, int N) {
  int i = blockIdx.x * blockDim.x + threadIdx.x;
  if (i >= (N + 1) * CIN) return;
  int r = i >> 6, c = i & 63;
  float v = (i < N * CIN) ? x[i] : 0.f;
  xbf[(size_t)r * CIN + (c & 32) + posf(c & 31)] = f2bf(v);
}

__global__ void cvt_weights(const float* __restrict__ W1, const float* __restrict__ W2,
                            const float* __restrict__ Wd, u16* __restrict__ W1t,
                            u16* __restrict__ W2t, u16* __restrict__ Wdt) {
  int i = blockIdx.x * blockDim.x + threadIdx.x;
  const int n1 = K27 * CIN * COUT;
  const int n2 = K27 * COUT * COUT;
  const int nd = CIN * COUT;
  if (i < n1) {
    int k = i / (CIN * COUT), rem = i % (CIN * COUT);
    int ci = rem / COUT, co = rem % COUT;
    W1t[(size_t)k * (COUT * CIN) + co * CIN + (ci & 32) + posf(ci & 31)] = f2bf(W1[i]);
  } else if (i < n1 + n2) {
    int t = i - n1;
    int k = t / (COUT * COUT), rem = t % (COUT * COUT);
    int ci = rem / COUT, co = rem % COUT;
    W2t[(size_t)k * (COUT * COUT) + co * COUT + (ci >> 5) * 32 + posf(ci & 31)] = f2bf(W2[t]);
  } else if (i < n1 + n2 + nd) {
    int t = i - n1 - n2;
    int ci = t / COUT, co = t % COUT;
    Wdt[co * CIN + (ci & 32) + posf(ci & 31)] = f2bf(Wd[t]);
  }
}

__global__ void bn_prep(const float* g1, const float* b1, const float* m1, const float* v1,
                        const float* g2, const float* b2, const float* m2, const float* v2,
                        const float* gd, const float* bd, const float* md, const float* vd,
                        float* __restrict__ bnc, u16* __restrict__ hbf, int N) {
  int c = threadIdx.x;
  if (c < COUT) {
    float A1 = g1[c] * rsqrtf(v1[c] + 1e-5f);
    float A2 = g2[c] * rsqrtf(v2[c] + 1e-5f);
    float Ad = gd[c] * rsqrtf(vd[c] + 1e-5f);
    bnc[c]       = A1;
    bnc[96 + c]  = b1[c] - m1[c] * A1;
    bnc[192 + c] = A2;
    bnc[288 + c] = b2[c] - m2[c] * A2 + bd[c] - md[c] * Ad;
    bnc[384 + c] = Ad / A2;
    hbf[(size_t)N * COUT + c] = 0;  // zero row for invalid gathers
  }
}

// ---------------- conv1: x(64) -> h(96) bf16, BN+ReLU, permuted store --------
__global__ __launch_bounds__(256, 4) void conv1_mfma(
    const u16* __restrict__ xbf, const u16* __restrict__ W1t,
    const int* __restrict__ nbT, const float* __restrict__ bnc,
    u16* __restrict__ hbf, int N, int N_pad) {
  const int lane = threadIdx.x & 63;
  const int m    = lane & 15;
  const int slot = (lane >> 4) & 3;
  const int so   = slot * 8;
  const int row0 = blockIdx.x * 64 + (int)(threadIdx.x >> 6) * 16;

  f32x4 acc[6];
#pragma unroll
  for (int n = 0; n < 6; ++n) acc[n] = (f32x4){0.f, 0.f, 0.f, 0.f};

  const int* nbp = nbT + row0 + m;
  const u16* wB  = W1t + m * CIN + so;

  int j1, j2;
  bf16x8 Aa[2], Ab[2];
  {
    int j0 = nbp[0];
    j1 = nbp[N_pad];
    j2 = nbp[2 * (size_t)N_pad];
    const u16* p = xbf + (size_t)(j0 < 0 ? N : j0) * CIN + so;
    Aa[0] = ld16(p); Aa[1] = ld16(p + 32);
  }

  auto step = [&](int k, bf16x8 (&Ac)[2], bf16x8 (&An)[2]) {
    const u16* wk = wB + (size_t)k * (COUT * CIN);
    bf16x8 B0[6], B1[6];
#pragma unroll
    for (int n = 0; n < 6; ++n) B0[n] = ld16(wk + n * (16 * CIN));
#pragma unroll
    for (int n = 0; n < 6; ++n) B1[n] = ld16(wk + n * (16 * CIN) + 32);
    int j3 = (k + 3 < K27) ? nbp[(size_t)(k + 3) * N_pad] : 0;
    if (k + 1 < K27) {
      const u16* p = xbf + (size_t)(j1 < 0 ? N : j1) * CIN + so;
      An[0] = ld16(p); An[1] = ld16(p + 32);
    }
    j1 = j2; j2 = j3;
#pragma unroll
    for (int n = 0; n < 6; ++n) acc[n] = MFMA(Ac[0], B0[n], acc[n], 0, 0, 0);
#pragma unroll
    for (int n = 0; n < 6; ++n) acc[n] = MFMA(Ac[1], B1[n], acc[n], 0, 0, 0);
  };

  for (int kk = 0; kk < K27 - 1; kk += 2) {
    step(kk, Aa, Ab);
    step(kk + 1, Ab, Aa);
  }
  step(K27 - 1, Aa, Ab);

  const int pbase = ((m >> 2) << 3) + (m & 3);
#pragma unroll
  for (int n = 0; n < 6; ++n) {
    const int col  = n * 16 + m;
    const int dcol = (n >> 1) * 32 + pbase + ((n & 1) << 2);  // permuted cin pos for conv2
    const float s = bnc[col], b = bnc[COUT + col];
#pragma unroll
    for (int r = 0; r < 4; ++r) {
      const int row = row0 + slot * 4 + r;
      if (row < N)
        hbf[(size_t)row * COUT + dcol] = f2bf(fmaxf(fmaf(acc[n][r], s, b), 0.f));
    }
  }
}

// ------- conv2: h(96) -> out(96) f32, + folded skip BN(x@Wd), BN+ReLU --------
__global__ __launch_bounds__(256, 4) void conv2_mfma(
    const u16* __restrict__ hbf, const u16* __restrict__ W2t,
    const u16* __restrict__ xbf, const u16* __restrict__ Wdt,
    const int* __restrict__ nbT, const float* __restrict__ bnc,
    float* __restrict__ out, int N, int N_pad) {
  const int lane = threadIdx.x & 63;
  const int m    = lane & 15;
  const int slot = (lane >> 4) & 3;
  const int so   = slot * 8;
  const int row0 = blockIdx.x * 64 + (int)(threadIdx.x >> 6) * 16;

  f32x4 acc[6];
#pragma unroll
  for (int n = 0; n < 6; ++n) acc[n] = (f32x4){0.f, 0.f, 0.f, 0.f};

  // skip path: x @ Wd on own rows, pre-scaled by Ad/A2
  {
    int r0 = row0 + m;
    const u16* p = xbf + (size_t)(r0 < N ? r0 : N) * CIN + so;
    bf16x8 S0 = ld16(p), S1 = ld16(p + 32);
    const u16* wd = Wdt + m * CIN + so;
#pragma unroll
    for (int n = 0; n < 6; ++n) {
      bf16x8 B0 = ld16(wd + n * (16 * CIN));
      bf16x8 B1 = ld16(wd + n * (16 * CIN) + 32);
      acc[n] = MFMA(S0, B0, acc[n], 0, 0, 0);
      acc[n] = MFMA(S1, B1, acc[n], 0, 0, 0);
    }
#pragma unroll
    for (int n = 0; n < 6; ++n) acc[n] *= bnc[384 + n * 16 + m];
  }

  const int* nbp = nbT + row0 + m;
  const u16* wB  = W2t + m * COUT + so;

  int j1, j2;
  bf16x8 Aa[3], Ab[3];
  {
    int j0 = nbp[0];
    j1 = nbp[N_pad];
    j2 = nbp[2 * (size_t)N_pad];
    const u16* p = hbf + (size_t)(j0 < 0 ? N : j0) * COUT + so;
    Aa[0] = ld16(p); Aa[1] = ld16(p + 32); Aa[2] = ld16(p + 64);
  }

  auto step = [&](int k, bf16x8 (&Ac)[3], bf16x8 (&An)[3]) {
    const u16* wk = wB + (size_t)k * (COUT * COUT);
    bf16x8 B0[6], B1[6];
#pragma unroll
    for (int n = 0; n < 6; ++n) B0[n] = ld16(wk + n * (16 * COUT));
#pragma unroll
    for (int n = 0; n < 6; ++n) B1[n] = ld16(wk + n * (16 * COUT) + 32);
    int j3 = (k + 3 < K27) ? nbp[(size_t)(k + 3) * N_pad] : 0;
    if (k + 1 < K27) {
      const u16* p = hbf + (size_t)(j1 < 0 ? N : j1) * COUT + so;
      An[0] = ld16(p); An[1] = ld16(p + 32); An[2] = ld16(p + 64);
    }
    j1 = j2; j2 = j3;
#pragma unroll
    for (int n = 0; n < 6; ++n) acc[n] = MFMA(Ac[0], B0[n], acc[n], 0, 0, 0);
#pragma unroll
    for (int n = 0; n < 6; ++n) acc[n] = MFMA(Ac[1], B1[n], acc[n], 0, 0, 0);
    bf16x8 B2[6];
#pragma unroll
    for (int n = 0; n < 6; ++n) B2[n] = ld16(wk + n * (16 * COUT) + 64);
#pragma unroll
    for (int n = 0; n < 6; ++n) acc[n] = MFMA(Ac[2], B2[n], acc[n], 0, 0, 0);
  };

  for (int kk = 0; kk < K27 - 1; kk += 2) {
    step(kk, Aa, Ab);
    step(kk + 1, Ab, Aa);
  }
  step(K27 - 1, Aa, Ab);

#pragma unroll
  for (int n = 0; n < 6; ++n) {
    const int col = n * 16 + m;
    const float s = bnc[192 + col], b = bnc[288 + col];
#pragma unroll
    for (int r = 0; r < 4; ++r) {
      const int row = row0 + slot * 4 + r;
      if (row < N)
        out[(size_t)row * COUT + col] = fmaxf(fmaf(acc[n][r], s, b), 0.f);
    }
  }
}

// ---------------- launch ----------------
extern "C" void kernel_launch(void* const* d_in, const int* in_sizes, int n_in,
                              void* d_out, int out_size, void* d_ws, size_t ws_size,
                              hipStream_t stream) {
  const float* x  = (const float*)d_in[0];
  const float* W1 = (const float*)d_in[1];
  const float* g1 = (const float*)d_in[2];
  const float* b1 = (const float*)d_in[3];
  const float* m1 = (const float*)d_in[4];
  const float* v1 = (const float*)d_in[5];
  const float* W2 = (const float*)d_in[6];
  const float* g2 = (const float*)d_in[7];
  const float* b2 = (const float*)d_in[8];
  const float* m2 = (const float*)d_in[9];
  const float* v2 = (const float*)d_in[10];
  const float* Wd = (const float*)d_in[11];
  const float* gd = (const float*)d_in[12];
  const float* bd = (const float*)d_in[13];
  const float* md = (const float*)d_in[14];
  const float* vd = (const float*)d_in[15];
  const int* in_idx  = (const int*)d_in[16];
  const int* out_idx = (const int*)d_in[17];

  const int N  = in_sizes[0] / CIN;
  const int GB = (N + 63) / 64;
  const int N_pad = GB * 64;

  char* ws = (char*)d_ws;
  size_t off = 0;
  auto alloc = [&](size_t bytes) { size_t o = off; off = (off + bytes + 255) & ~(size_t)255; return o; };
  int*   nbT = (int*)(ws + alloc((size_t)K27 * N_pad * sizeof(int)));
  u16*   xbf = (u16*)(ws + alloc((size_t)(N + 1) * CIN * sizeof(u16)));
  u16*   hbf = (u16*)(ws + alloc((size_t)(N + 1) * COUT * sizeof(u16)));
  u16*   W1t = (u16*)(ws + alloc((size_t)K27 * COUT * CIN * sizeof(u16)));
  u16*   W2t = (u16*)(ws + alloc((size_t)K27 * COUT * COUT * sizeof(u16)));
  u16*   Wdt = (u16*)(ws + alloc((size_t)COUT * CIN * sizeof(u16)));
  float* bnc = (float*)(ws + alloc(5 * 96 * sizeof(float)));

  hipMemsetAsync(nbT, 0xFF, (size_t)K27 * N_pad * sizeof(int), stream);
  build_nbT<<<(K27 * N + 255) / 256, 256, 0, stream>>>(in_idx, out_idx, nbT, N, N_pad);
  cvt_x<<<((N + 1) * CIN + 255) / 256, 256, 0, stream>>>(x, xbf, N);
  const int wtot = K27 * CIN * COUT + K27 * COUT * COUT + CIN * COUT;
  cvt_weights<<<(wtot + 255) / 256, 256, 0, stream>>>(W1, W2, Wd, W1t, W2t, Wdt);
  bn_prep<<<1, 128, 0, stream>>>(g1, b1, m1, v1, g2, b2, m2, v2, gd, bd, md, vd, bnc, hbf, N);

  conv1_mfma<<<GB, 256, 0, stream>>>(xbf, W1t, nbT, bnc, hbf, N, N_pad);
  conv2_mfma<<<GB, 256, 0, stream>>>(hbf, W2t, xbf, Wdt, nbT, bnc, (float*)d_out, N, N_pad);
}

// Round 4
// 125.079 us; speedup vs baseline: 5.2936x; 2.6319x over previous
//
#include <hip/hip_runtime.h>

// Sparse residual block via bf16 MFMA, output-centric.
// Round 4: 2-phase LDS double-buffered weights (global_load_lds w=16),
// XOR-swizzled ds_read (byte ^= (row&7)<<4), register-gathered A with prefetch.

typedef __attribute__((ext_vector_type(8))) short bf16x8;
typedef __attribute__((ext_vector_type(4))) float f32x4;
typedef unsigned short u16;

constexpr int K27  = 27;
constexpr int CIN  = 64;
constexpr int COUT = 96;

#define MFMA __builtin_amdgcn_mfma_f32_16x16x32_bf16

__device__ __forceinline__ u16 f2bf(float f) {
  unsigned u = __float_as_uint(f);
  return (u16)((u + 0x7FFFu + ((u >> 16) & 1u)) >> 16);
}

__device__ __forceinline__ int posf(int c) {  // c in 0..31, k_local-ordered perm
  return ((c >> 2) & 3) * 8 + (c & 3) + ((c >> 4) & 1) * 4;
}

__device__ __forceinline__ bf16x8 ld16(const u16* p) {
  union { bf16x8 f; uint4 u; } r;
  r.u = *reinterpret_cast<const uint4*>(p);
  return r.f;
}

// async global->LDS, 16B/lane, linear dest (source layout carries the swizzle)
template <int NS>
__device__ __forceinline__ void stageB(const u16* g, u16* l, int t) {
#pragma unroll
  for (int s = 0; s < NS; ++s) {
    __builtin_amdgcn_global_load_lds(
        (const __attribute__((address_space(1))) unsigned int*)(g + s * 2048 + t * 8),
        (__attribute__((address_space(3))) unsigned int*)(l + s * 2048 + t * 8),
        16, 0, 0);
  }
}

// ---------------- prep ----------------
__global__ void build_nbT(const int* __restrict__ in_idx, const int* __restrict__ out_idx,
                          int* __restrict__ nbT, int N, int N_pad) {
  int t = blockIdx.x * blockDim.x + threadIdx.x;
  if (t >= K27 * N) return;
  int k = t / N;
  int o = out_idx[t];
  if (o < N) nbT[(size_t)k * N_pad + o] = in_idx[t];
}

__global__ void prep_all(
    const float* __restrict__ x, const float* __restrict__ W1,
    const float* __restrict__ W2, const float* __restrict__ Wd,
    const float* g1, const float* b1, const float* m1, const float* v1,
    const float* g2, const float* b2, const float* m2, const float* v2,
    const float* gd, const float* bd, const float* md, const float* vd,
    u16* __restrict__ xbf, u16* __restrict__ W1t, u16* __restrict__ W2t,
    u16* __restrict__ Wdt, float* __restrict__ bnc, u16* __restrict__ hbf, int N) {
  long i = (long)blockIdx.x * blockDim.x + threadIdx.x;
  const long R0 = (long)(N + 1) * CIN;
  const long R1 = (long)K27 * CIN * COUT;
  const long R2 = (long)K27 * COUT * COUT;
  const long R3 = (long)CIN * COUT;
  if (i < R0) {  // x -> bf16, permuted channels; row N zeroed
    int c = (int)(i & 63);
    float v = (i < (long)N * CIN) ? x[i] : 0.f;
    xbf[(i & ~63L) + (c & 32) + posf(c & 31)] = f2bf(v);
    return;
  }
  i -= R0;
  if (i < R1) {  // W1[k][ci][co] -> W1t[k][co][swz(perm(ci))], row=64 u16
    int k = (int)(i / (CIN * COUT)), rem = (int)(i % (CIN * COUT));
    int ci = rem / COUT, co = rem % COUT;
    int cidx = (ci & 32) + posf(ci & 31);
    W1t[(size_t)k * 6144 + co * 64 + (cidx ^ ((co & 7) << 3))] = f2bf(W1[i]);
    return;
  }
  i -= R1;
  if (i < R2) {  // W2[k][ci][co] -> W2t[k][co][swz(perm(ci))], row padded to 128 u16
    int k = (int)(i / (COUT * COUT)), rem = (int)(i % (COUT * COUT));
    int ci = rem / COUT, co = rem % COUT;
    int cidx = (ci >> 5) * 32 + posf(ci & 31);
    W2t[(size_t)k * 12288 + co * 128 + (cidx ^ ((co & 7) << 3))] = f2bf(W2[i]);
    return;
  }
  i -= R2;
  if (i < R3) {  // Wd[ci][co] -> Wdt[co][perm(ci)] (register path, no swizzle)
    int ci = (int)(i / COUT), co = (int)(i % COUT);
    Wdt[co * CIN + (ci & 32) + posf(ci & 31)] = f2bf(Wd[i]);
    return;
  }
  i -= R3;
  if (i < COUT) {  // BN constants + zero row of hbf
    int c = (int)i;
    float A1 = g1[c] * rsqrtf(v1[c] + 1e-5f);
    float A2 = g2[c] * rsqrtf(v2[c] + 1e-5f);
    float Ad = gd[c] * rsqrtf(vd[c] + 1e-5f);
    bnc[c]       = A1;
    bnc[96 + c]  = b1[c] - m1[c] * A1;
    bnc[192 + c] = A2;
    bnc[288 + c] = b2[c] - m2[c] * A2 + bd[c] - md[c] * Ad;
    bnc[384 + c] = Ad / A2;
    hbf[(size_t)N * COUT + c] = 0;
  }
}

// ---------------- conv1: x(64) -> h(96) bf16, BN+ReLU, permuted store --------
__global__ __launch_bounds__(256, 2) void conv1_mfma(
    const u16* __restrict__ xbf, const u16* __restrict__ W1t,
    const int* __restrict__ nbT, const float* __restrict__ bnc,
    u16* __restrict__ hbf, int N, int N_pad) {
  __shared__ u16 Blds[2][6144];
  const int t    = threadIdx.x;
  const int lane = t & 63;
  const int m    = lane & 15;
  const int slot = lane >> 4;
  const int so   = slot * 8;
  const int sw   = (m & 7) << 3;
  const int row0 = blockIdx.x * 64 + (t >> 6) * 16;

  f32x4 acc[6];
#pragma unroll
  for (int n = 0; n < 6; ++n) acc[n] = (f32x4){0.f, 0.f, 0.f, 0.f};

  const int* nbp = nbT + row0 + m;

  stageB<3>(W1t, Blds[0], t);                 // k=0 tile
  int j1 = nbp[N_pad];
  int j2 = nbp[2 * (size_t)N_pad];
  bf16x8 Aa[2], Ab[2];
  {
    int j0 = nbp[0];
    const u16* p = xbf + (size_t)(j0 < 0 ? N : j0) * CIN + so;
    Aa[0] = ld16(p); Aa[1] = ld16(p + 32);
  }
  __syncthreads();                            // buf0 staged, A(0) landed

  auto step = [&](int k, bf16x8 (&Ac)[2], bf16x8 (&An)[2]) {
    const int cur = k & 1;
    if (k + 1 < K27) stageB<3>(W1t + (size_t)(k + 1) * 6144, Blds[cur ^ 1], t);
    int jn = j1; j1 = j2;
    j2 = (k + 3 < K27) ? nbp[(size_t)(k + 3) * N_pad] : 0;
    if (k + 1 < K27) {
      const u16* p = xbf + (size_t)(jn < 0 ? N : jn) * CIN + so;
      An[0] = ld16(p); An[1] = ld16(p + 32);
    }
    const u16* Bb = Blds[cur];
#pragma unroll
    for (int c = 0; c < 2; ++c)
#pragma unroll
      for (int n = 0; n < 6; ++n) {
        bf16x8 B = ld16(Bb + n * 1024 + m * 64 + ((c * 32 + so) ^ sw));
        acc[n] = MFMA(Ac[c], B, acc[n], 0, 0, 0);
      }
    __syncthreads();                          // next buf staged & prior reads done
  };

  for (int kk = 0; kk < K27 - 1; kk += 2) {
    step(kk, Aa, Ab);
    step(kk + 1, Ab, Aa);
  }
  step(K27 - 1, Aa, Ab);

  const int pbase = ((m >> 2) << 3) + (m & 3);
#pragma unroll
  for (int n = 0; n < 6; ++n) {
    const int col  = n * 16 + m;
    const int dcol = (n >> 1) * 32 + pbase + ((n & 1) << 2);  // permuted pos for conv2 A
    const float s = bnc[col], b = bnc[COUT + col];
#pragma unroll
    for (int r = 0; r < 4; ++r) {
      const int row = row0 + slot * 4 + r;
      if (row < N)
        hbf[(size_t)row * COUT + dcol] = f2bf(fmaxf(fmaf(acc[n][r], s, b), 0.f));
    }
  }
}

// ------- conv2: h(96) -> out(96) f32, + folded skip BN(x@Wd), BN+ReLU --------
__global__ __launch_bounds__(256, 2) void conv2_mfma(
    const u16* __restrict__ hbf, const u16* __restrict__ W2t,
    const u16* __restrict__ xbf, const u16* __restrict__ Wdt,
    const int* __restrict__ nbT, const float* __restrict__ bnc,
    float* __restrict__ out, int N, int N_pad) {
  __shared__ u16 Blds[2][12288];
  const int t    = threadIdx.x;
  const int lane = t & 63;
  const int m    = lane & 15;
  const int slot = lane >> 4;
  const int so   = slot * 8;
  const int sw   = (m & 7) << 3;
  const int row0 = blockIdx.x * 64 + (t >> 6) * 16;

  f32x4 acc[6];
#pragma unroll
  for (int n = 0; n < 6; ++n) acc[n] = (f32x4){0.f, 0.f, 0.f, 0.f};

  stageB<6>(W2t, Blds[0], t);                 // k=0 tile (overlaps skip path)

  // skip path: x @ Wd on own rows, pre-scaled by Ad/A2
  {
    int r0 = row0 + m;
    const u16* p = xbf + (size_t)(r0 < N ? r0 : N) * CIN + so;
    bf16x8 S0 = ld16(p), S1 = ld16(p + 32);
    const u16* wd = Wdt + m * CIN + so;
#pragma unroll
    for (int n = 0; n < 6; ++n) {
      bf16x8 B0 = ld16(wd + n * (16 * CIN));
      bf16x8 B1 = ld16(wd + n * (16 * CIN) + 32);
      acc[n] = MFMA(S0, B0, acc[n], 0, 0, 0);
      acc[n] = MFMA(S1, B1, acc[n], 0, 0, 0);
    }
#pragma unroll
    for (int n = 0; n < 6; ++n) acc[n] *= bnc[384 + n * 16 + m];
  }

  const int* nbp = nbT + row0 + m;
  int j1 = nbp[N_pad];
  int j2 = nbp[2 * (size_t)N_pad];
  bf16x8 Aa[3], Ab[3];
  {
    int j0 = nbp[0];
    const u16* p = hbf + (size_t)(j0 < 0 ? N : j0) * COUT + so;
    Aa[0] = ld16(p); Aa[1] = ld16(p + 32); Aa[2] = ld16(p + 64);
  }
  __syncthreads();

  auto step = [&](int k, bf16x8 (&Ac)[3], bf16x8 (&An)[3]) {
    const int cur = k & 1;
    if (k + 1 < K27) stageB<6>(W2t + (size_t)(k + 1) * 12288, Blds[cur ^ 1], t);
    int jn = j1; j1 = j2;
    j2 = (k + 3 < K27) ? nbp[(size_t)(k + 3) * N_pad] : 0;
    if (k + 1 < K27) {
      const u16* p = hbf + (size_t)(jn < 0 ? N : jn) * COUT + so;
      An[0] = ld16(p); An[1] = ld16(p + 32); An[2] = ld16(p + 64);
    }
    const u16* Bb = Blds[cur];
#pragma unroll
    for (int c = 0; c < 3; ++c)
#pragma unroll
      for (int n = 0; n < 6; ++n) {
        bf16x8 B = ld16(Bb + n * 2048 + m * 128 + ((c * 32 + so) ^ sw));
        acc[n] = MFMA(Ac[c], B, acc[n], 0, 0, 0);
      }
    __syncthreads();
  };

  for (int kk = 0; kk < K27 - 1; kk += 2) {
    step(kk, Aa, Ab);
    step(kk + 1, Ab, Aa);
  }
  step(K27 - 1, Aa, Ab);

#pragma unroll
  for (int n = 0; n < 6; ++n) {
    const int col = n * 16 + m;
    const float s = bnc[192 + col], b = bnc[288 + col];
#pragma unroll
    for (int r = 0; r < 4; ++r) {
      const int row = row0 + slot * 4 + r;
      if (row < N)
        out[(size_t)row * COUT + col] = fmaxf(fmaf(acc[n][r], s, b), 0.f);
    }
  }
}

// ---------------- launch ----------------
extern "C" void kernel_launch(void* const* d_in, const int* in_sizes, int n_in,
                              void* d_out, int out_size, void* d_ws, size_t ws_size,
                              hipStream_t stream) {
  const float* x  = (const float*)d_in[0];
  const float* W1 = (const float*)d_in[1];
  const float* g1 = (const float*)d_in[2];
  const float* b1 = (const float*)d_in[3];
  const float* m1 = (const float*)d_in[4];
  const float* v1 = (const float*)d_in[5];
  const float* W2 = (const float*)d_in[6];
  const float* g2 = (const float*)d_in[7];
  const float* b2 = (const float*)d_in[8];
  const float* m2 = (const float*)d_in[9];
  const float* v2 = (const float*)d_in[10];
  const float* Wd = (const float*)d_in[11];
  const float* gd = (const float*)d_in[12];
  const float* bd = (const float*)d_in[13];
  const float* md = (const float*)d_in[14];
  const float* vd = (const float*)d_in[15];
  const int* in_idx  = (const int*)d_in[16];
  const int* out_idx = (const int*)d_in[17];

  const int N  = in_sizes[0] / CIN;
  const int GB = (N + 63) / 64;
  const int N_pad = GB * 64;

  char* ws = (char*)d_ws;
  size_t off = 0;
  auto alloc = [&](size_t bytes) { size_t o = off; off = (off + bytes + 255) & ~(size_t)255; return o; };
  int*   nbT = (int*)(ws + alloc((size_t)K27 * N_pad * sizeof(int)));
  u16*   xbf = (u16*)(ws + alloc((size_t)(N + 1) * CIN * sizeof(u16)));
  u16*   hbf = (u16*)(ws + alloc((size_t)(N + 1) * COUT * sizeof(u16)));
  u16*   W1t = (u16*)(ws + alloc((size_t)K27 * 6144 * sizeof(u16)));
  u16*   W2t = (u16*)(ws + alloc((size_t)K27 * 12288 * sizeof(u16)));   // padded rows
  u16*   Wdt = (u16*)(ws + alloc((size_t)COUT * CIN * sizeof(u16)));
  float* bnc = (float*)(ws + alloc(5 * 96 * sizeof(float)));

  hipMemsetAsync(nbT, 0xFF, (size_t)K27 * N_pad * sizeof(int), stream);
  build_nbT<<<(K27 * N + 255) / 256, 256, 0, stream>>>(in_idx, out_idx, nbT, N, N_pad);

  long ptotal = (long)(N + 1) * CIN + (long)K27 * CIN * COUT +
                (long)K27 * COUT * COUT + (long)CIN * COUT + COUT;
  prep_all<<<(int)((ptotal + 255) / 256), 256, 0, stream>>>(
      x, W1, W2, Wd, g1, b1, m1, v1, g2, b2, m2, v2, gd, bd, md, vd,
      xbf, W1t, W2t, Wdt, bnc, hbf, N);

  conv1_mfma<<<GB, 256, 0, stream>>>(xbf, W1t, nbT, bnc, hbf, N, N_pad);
  conv2_mfma<<<GB, 256, 0, stream>>>(hbf, W2t, xbf, Wdt, nbT, bnc, (float*)d_out, N, N_pad);
}